// Round 4
// baseline (224.188 us; speedup 1.0000x reference)
//
#include <hip/hip_runtime.h>
#include <hip/hip_bf16.h>
#include <cstddef>

// Problem constants (from reference setup_inputs)
#define BB 16
#define CC 192
#define HH 64
#define WW 64
#define LL 4096   // H*W
#define DTR 12    // dt_rank
#define KK 14     // dt_rank + 2*d_state, d_state = 1

__device__ __forceinline__ float silu_f(float v) {
  return v / (1.f + __expf(-v));
}

// ---------------------------------------------------------------------------
// K1 (FUSED): depthwise 5x5 conv + SiLU + x_proj + dt-projection + softplus.
// Grid (32 strips, 16 b), 512 threads = 8 waves. Strip s = image rows
// {2s, 2s+1} = l in [128s, 128s+128). Wave g owns channels g*24..g*24+23;
// lane = column. Per channel: load 6 halo rows (zero-padded), shuffle for
// x-halo, 2x25 FMA conv, SiLU, store xs, and accumulate the 14 x_proj
// dot-products in registers (weights via wave-uniform scalar loads).
// Cross-wave c-reduction: atomicAdd into a 7 KB LDS tile (ds_add_f32) —
// was a 59 KB part[8] buffer that capped occupancy at 2 blocks/CU.
// Phase 2 (unchanged math): per-thread dts[12] from LDS, emit
// delta = softplus(dt_w . dts + dt_b) for 48 channels; group 3 writes B/C.
// Deletes the standalone conv kernel: one fewer 50 MB read pass and one
// fewer ~42 us latency-bound dispatch.
// ---------------------------------------------------------------------------
__global__ __launch_bounds__(512) void convprojdt_kernel(
    const float* __restrict__ x, const float* __restrict__ cw,
    const float* __restrict__ cb, const float* __restrict__ xpw,
    const float* __restrict__ dtw, const float* __restrict__ dtb,
    float* __restrict__ xs, float* __restrict__ delta,
    float* __restrict__ Bsp, float* __restrict__ Csp) {
  const int b = blockIdx.y;
  const int s = blockIdx.x;            // strip: rows 2s, 2s+1
  const int l0 = s * 128;
  const int y0 = s * 2;
  const int tid = threadIdx.x;
  const int lane = tid & 63;           // column 0..63
  const int g = tid >> 6;              // wave 0..7 (wave-uniform)

  __shared__ float dts_lds[KK][128];
  for (int i = tid; i < KK * 128; i += 512) ((float*)dts_lds)[i] = 0.f;
  __syncthreads();

  float2 acc[KK];
#pragma unroll
  for (int k = 0; k < KK; ++k) acc[k] = make_float2(0.f, 0.f);

  const int c0 = g * 24;
#pragma unroll 2
  for (int cc = 0; cc < 24; ++cc) {
    const int c = c0 + cc;             // wave-uniform -> scalar weight loads
    const float* xpp = x + ((size_t)(b * CC + c)) * LL + lane;
    // 6 input rows y0-2 .. y0+3, zero outside [0,64)
    float r[6];
#pragma unroll
    for (int j = 0; j < 6; ++j) {
      const int gy = y0 - 2 + j;
      r[j] = ((unsigned)gy < 64u) ? xpp[gy * 64] : 0.f;
    }
    float s0 = cb[c], s1 = cb[c];
#pragma unroll
    for (int j = 0; j < 6; ++j) {
      float v = r[j];
      float vm2 = __shfl_up(v, 2u, 64);
      float vm1 = __shfl_up(v, 1u, 64);
      float vp1 = __shfl_down(v, 1u, 64);
      float vp2 = __shfl_down(v, 2u, 64);
      if (lane < 2) vm2 = 0.f;
      if (lane < 1) vm1 = 0.f;
      if (lane > 62) vp1 = 0.f;
      if (lane > 61) vp2 = 0.f;
      float t[5] = {vm2, vm1, v, vp1, vp2};
      if (j < 5) {                       // output row y0, ky = j
#pragma unroll
        for (int kx = 0; kx < 5; ++kx) s0 += cw[c * 25 + j * 5 + kx] * t[kx];
      }
      if (j >= 1) {                      // output row y0+1, ky = j-1
#pragma unroll
        for (int kx = 0; kx < 5; ++kx)
          s1 += cw[c * 25 + (j - 1) * 5 + kx] * t[kx];
      }
    }
    const float v0 = silu_f(s0);
    const float v1 = silu_f(s1);
    float* xsp = xs + ((size_t)(b * CC + c)) * LL + l0 + lane;
    xsp[0] = v0;
    xsp[64] = v1;
#pragma unroll
    for (int k = 0; k < KK; ++k) {
      const float wv = xpw[k * CC + c];
      acc[k].x += wv * v0;
      acc[k].y += wv * v1;
    }
  }

  // cross-wave reduction: 28 LDS float-atomics per thread (ds_add_f32)
#pragma unroll
  for (int k = 0; k < KK; ++k) {
    atomicAdd(&dts_lds[k][lane], acc[k].x);
    atomicAdd(&dts_lds[k][64 + lane], acc[k].y);
  }
  __syncthreads();

  // ---- phase 2: dt-projection + softplus ----
  const int l = tid & 127;
  const int cg = tid >> 7;   // 0..3 (wave-uniform: 2 waves per group)
  float dts[DTR];
#pragma unroll
  for (int r = 0; r < DTR; ++r) dts[r] = dts_lds[r][l];
  if (cg == 3) {  // one group emits the tiny B/C planes
    Bsp[(size_t)b * LL + l0 + l] = dts_lds[12][l];
    Csp[(size_t)b * LL + l0 + l] = dts_lds[13][l];
  }
  float* dp = delta + ((size_t)b * CC + cg * 48) * LL + l0 + l;
  for (int i = 0; i < 48; ++i) {
    const int c = cg * 48 + i;         // wave-uniform -> scalar weight loads
    float z = dtb[c];
#pragma unroll
    for (int r = 0; r < DTR; ++r) z += dtw[c * DTR + r] * dts[r];
    float d = (z > 15.f) ? z : __logf(1.f + __expf(z));
    dp[(size_t)i * LL] = d;
  }
}

// ---------------------------------------------------------------------------
// K2: selective scan + output. 4 waves per (b,c), segment-parallel; per chunk
// four float4 loads (delta, x, B, C), 6-step shuffle scan, u/v epilogue with
// 8-float LDS segment-carry exchange.  (unchanged this round)
// ---------------------------------------------------------------------------
__global__ __launch_bounds__(256) void scan_kernel(
    const float* __restrict__ xs, const float* __restrict__ delta,
    const float* __restrict__ Bsp, const float* __restrict__ Csp,
    const float* __restrict__ A_logs, const float* __restrict__ Ds,
    float* __restrict__ y) {
  const int bc = blockIdx.x;
  const int b = bc / CC;
  const int c = bc - b * CC;
  const int tid = threadIdx.x;
  const int lane = tid & 63;
  const int wv = tid >> 6;  // wave 0..3, owns segment [1024*wv, 1024*wv+1023]

  const float Ac = -__expf(A_logs[c]);  // d_state = 1
  const float Dc = Ds[c];

  const float* xp = xs + (size_t)bc * LL;
  const float* ddp = delta + (size_t)bc * LL;
  const float* bpp = Bsp + (size_t)b * LL;
  const float* cpp = Csp + (size_t)b * LL;
  float* yp = y + (size_t)bc * LL;

  __shared__ float segA[4];
  __shared__ float segB[4];

  float PA = 1.f;   // product of a's over processed part of this segment
  float hB = 0.f;   // h assuming zero state at segment start
  float u[16], v[16];

#pragma unroll
  for (int ck = 0; ck < 4; ++ck) {
    const int base = wv * 1024 + ck * 256 + lane * 4;
    const float4 x4 = *(const float4*)(xp + base);
    const float4 d4 = *(const float4*)(ddp + base);
    const float4 B4 = *(const float4*)(bpp + base);
    const float4 C4 = *(const float4*)(cpp + base);

    float av[4], bv[4];
    float aggA = 1.f, aggB = 0.f;
#pragma unroll
    for (int q = 0; q < 4; ++q) {
      const float dl = (&d4.x)[q];
      float a = __expf(dl * Ac);
      float be = dl * ((&B4.x)[q]) * ((&x4.x)[q]);
      av[q] = a;
      bv[q] = be;
      aggA = a * aggA;
      aggB = a * aggB + be;
    }

    // 6-step Hillis-Steele inclusive scan of (aggA, aggB) across lanes
    float incA = aggA, incB = aggB;
#pragma unroll
    for (int st = 1; st < 64; st <<= 1) {
      float pA = __shfl_up(incA, (unsigned)st, 64);
      float pB = __shfl_up(incB, (unsigned)st, 64);
      if (lane >= st) {
        incB = incA * pB + incB;
        incA = incA * pA;
      }
    }
    float eA = __shfl_up(incA, 1u, 64);
    float eB = __shfl_up(incB, 1u, 64);
    if (lane == 0) { eA = 1.f; eB = 0.f; }
    const float tA = __shfl(incA, 63, 64);
    const float tB = __shfl(incB, 63, 64);

    // lane's chunk-entry state relative to SEGMENT start
    float h = eA * hB + eB;   // local h at chunk entry
    float P = PA * eA;        // cumulative a-product at chunk entry
#pragma unroll
    for (int q = 0; q < 4; ++q) {
      h = av[q] * h + bv[q];
      P = P * av[q];
      u[ck * 4 + q] = P * ((&C4.x)[q]);
      v[ck * 4 + q] = h * ((&C4.x)[q]) + ((&x4.x)[q]) * Dc;
    }

    // advance segment-local running state (tA/tB are lane-uniform)
    hB = tA * hB + tB;
    PA = PA * tA;
  }

  if (lane == 0) { segA[wv] = PA; segB[wv] = hB; }
  __syncthreads();

  // carry into this wave's segment: fold segments 0..wv-1 in order
  float carry = 0.f;
  for (int i = 0; i < wv; ++i) carry = segA[i] * carry + segB[i];

#pragma unroll
  for (int ck = 0; ck < 4; ++ck) {
    const int base = wv * 1024 + ck * 256 + lane * 4;
    float4 o;
    o.x = u[ck * 4 + 0] * carry + v[ck * 4 + 0];
    o.y = u[ck * 4 + 1] * carry + v[ck * 4 + 1];
    o.z = u[ck * 4 + 2] * carry + v[ck * 4 + 2];
    o.w = u[ck * 4 + 3] * carry + v[ck * 4 + 3];
    *(float4*)(yp + base) = o;
  }
}

// ---------------------------------------------------------------------------
extern "C" void kernel_launch(void* const* d_in, const int* in_sizes, int n_in,
                              void* d_out, int out_size, void* d_ws,
                              size_t ws_size, hipStream_t stream) {
  const float* x        = (const float*)d_in[0];
  const float* conv_w   = (const float*)d_in[1];
  const float* conv_b   = (const float*)d_in[2];
  const float* x_proj_w = (const float*)d_in[3];
  const float* dt_w     = (const float*)d_in[4];
  const float* dt_b     = (const float*)d_in[5];
  const float* A_logs   = (const float*)d_in[6];
  const float* Ds       = (const float*)d_in[7];
  float* out = (float*)d_out;

  char* ws = (char*)d_ws;
  const size_t plane_bytes = (size_t)BB * CC * LL * sizeof(float);  // 50.3 MB
  const size_t bl_bytes    = (size_t)BB * LL * sizeof(float);       // 256 KB
  float* xs    = (float*)ws;
  float* delta = (float*)(ws + plane_bytes);
  float* Bsp   = (float*)(ws + 2 * plane_bytes);
  float* Csp   = (float*)(ws + 2 * plane_bytes + bl_bytes);

  convprojdt_kernel<<<dim3(LL / 128, BB), 512, 0, stream>>>(
      x, conv_w, conv_b, x_proj_w, dt_w, dt_b, xs, delta, Bsp, Csp);
  scan_kernel<<<dim3(BB * CC), 256, 0, stream>>>(xs, delta, Bsp, Csp,
                                                 A_logs, Ds, out);
}